// Round 14
// baseline (156.526 us; speedup 1.0000x reference)
//
#include <hip/hip_runtime.h>
#include <hip/hip_bf16.h>

#define BS    32
#define LSEQ  512
#define DIM   512
#define NCH   32
#define NDICT 97

// 2*log2(e): tanh(x) = 1 - 2*sigmoid(-2x); sigmoid(-2x) = 1/(1+2^(x*2*log2e))
#define TANH_SCALE 2.8853900817779268f

typedef __attribute__((ext_vector_type(8))) short bf16x8;
typedef __attribute__((ext_vector_type(4))) float f32x4;

#define GLDS16(gsrc, ldst) \
  __builtin_amdgcn_global_load_lds((const __attribute__((address_space(1))) void*)(gsrc), \
                                   (__attribute__((address_space(3))) void*)(ldst), 16, 0, 0)

__device__ __forceinline__ float sig_from_scaled(float xs) {
    float e2 = __builtin_amdgcn_exp2f(xs);
    return __builtin_amdgcn_rcpf(1.0f + e2);
}

__device__ __forceinline__ void split2u(float x0, float x1, unsigned& hp, unsigned& lp) {
    unsigned r0 = __float_as_uint(x0) + 0x8000u;
    unsigned r1 = __float_as_uint(x1) + 0x8000u;
    float f0 = __uint_as_float(r0 & 0xFFFF0000u);
    float f1 = __uint_as_float(r1 & 0xFFFF0000u);
    hp = (r0 >> 16) | (r1 & 0xFFFF0000u);
    unsigned s0 = __float_as_uint(x0 - f0);
    unsigned s1 = __float_as_uint(x1 - f1);
    lp = (s0 >> 16) | (s1 & 0xFFFF0000u);
}

__device__ __forceinline__ float sig4(float4 wo, float4 wv, float4 we, float s) {
    s = fmaf(we.x, sig_from_scaled(wo.x + wv.x), s);
    s = fmaf(we.y, sig_from_scaled(wo.y + wv.y), s);
    s = fmaf(we.z, sig_from_scaled(wo.z + wv.z), s);
    s = fmaf(we.w, sig_from_scaled(wo.w + wv.w), s);
    return s;
}

// folding tree over 16 chars across the 16 d-lanes (j = lane&15); lane j gets char j's sum
__device__ __forceinline__ float tree16(const float* sv, int j) {
    float t2[8];
    #pragma unroll
    for (int i = 0; i < 8; ++i) {
        float a = sv[2 * i]     + __shfl_xor(sv[2 * i],     1, 64);
        float c = sv[2 * i + 1] + __shfl_xor(sv[2 * i + 1], 1, 64);
        t2[i] = (j & 1) ? c : a;
    }
    float t4[4];
    #pragma unroll
    for (int i = 0; i < 4; ++i) {
        float a = t2[2 * i]     + __shfl_xor(t2[2 * i],     2, 64);
        float c = t2[2 * i + 1] + __shfl_xor(t2[2 * i + 1], 2, 64);
        t4[i] = (j & 2) ? c : a;
    }
    float t8[2];
    #pragma unroll
    for (int i = 0; i < 2; ++i) {
        float a = t4[2 * i]     + __shfl_xor(t4[2 * i],     4, 64);
        float c = t4[2 * i + 1] + __shfl_xor(t4[2 * i + 1], 4, 64);
        t8[i] = (j & 4) ? c : a;
    }
    float a = t8[0] + __shfl_xor(t8[0], 8, 64);
    float c = t8[1] + __shfl_xor(t8[1], 8, 64);
    return (j & 8) ? c : a;
}

// ---------------- k_prep (weights): 0..63: Wv*SCALE -> B^T hi/lo; 64..127: Wo*SCALE -> Wo^T;
//                  block 128: emb -> hi/lo planes.
__global__ __launch_bounds__(256) void k_prep(
    const float* __restrict__ Wv, ushort* __restrict__ BhiT, ushort* __restrict__ BloT,
    const float* __restrict__ Wo, ushort* __restrict__ WohiT, ushort* __restrict__ WoloT,
    const float* __restrict__ emb, ushort* __restrict__ embH, ushort* __restrict__ embL)
{
    __shared__ float tile[64][65];
    const int bid = blockIdx.x;
    const int t = threadIdx.x;
    if (bid < 128) {
        const bool isWv = bid < 64;
        const float* src = isWv ? Wv : Wo;
        ushort* dH = isWv ? BhiT : WohiT;
        ushort* dL = isWv ? BloT : WoloT;
        const int bb = bid & 63;
        const int k0 = (bb >> 3) * 64, n0 = (bb & 7) * 64;
        const int tr = t >> 4, tc = (t & 15) * 4;
        #pragma unroll
        for (int rr = 0; rr < 64; rr += 16) {
            float4 v = *(const float4*)&src[(size_t)(k0 + rr + tr) * DIM + n0 + tc];
            tile[rr + tr][tc + 0] = v.x; tile[rr + tr][tc + 1] = v.y;
            tile[rr + tr][tc + 2] = v.z; tile[rr + tr][tc + 3] = v.w;
        }
        __syncthreads();
        #pragma unroll
        for (int rr = 0; rr < 64; rr += 16) {
            const int n = rr + tr;
            unsigned h01, l01, h23, l23;
            split2u(tile[tc + 0][n] * TANH_SCALE, tile[tc + 1][n] * TANH_SCALE, h01, l01);
            split2u(tile[tc + 2][n] * TANH_SCALE, tile[tc + 3][n] * TANH_SCALE, h23, l23);
            *(uint2*)&dH[(size_t)(n0 + n) * DIM + k0 + tc] = make_uint2(h01, h23);
            *(uint2*)&dL[(size_t)(n0 + n) * DIM + k0 + tc] = make_uint2(l01, l23);
        }
    } else {
        for (int i = t; i < 4096; i += 256) {
            float4 v = ((const float4*)emb)[i];
            unsigned h01, l01, h23, l23;
            split2u(v.x, v.y, h01, l01);
            split2u(v.z, v.w, h23, l23);
            ((uint2*)embH)[i] = make_uint2(h01, h23);
            ((uint2*)embL)[i] = make_uint2(l01, l23);
        }
    }
}

// ---------------- k_wo: w_o = SCALE*(emb @ Wo + b), [32][512] fp32. 4 blocks x 128 cols.
__global__ __launch_bounds__(256) void k_wo(
    const ushort* __restrict__ WohiT, const ushort* __restrict__ WoloT,
    const ushort* __restrict__ embH, const ushort* __restrict__ embL,
    const float* __restrict__ Wo_b, float* __restrict__ w_o)
{
    __shared__ ushort BhS[4096], BlS[4096];
    const int t = threadIdx.x;
    const int wave = t >> 6, lane = t & 63;
    const int sgB = (lane & 3) ^ ((lane >> 3) & 3);
    const int fr = lane & 15;
    const int q  = lane >> 4;
    const int fswzB = (q ^ ((fr >> 1) & 3)) * 8;
    const int nb0 = blockIdx.x * 128;
    const int crow0 = (wave * 32 + fr) * 32;
    f32x4 acc[2][2] = {};

    for (int k0 = 0; k0 < DIM; k0 += 32) {
        #pragma unroll
        for (int c4 = 0; c4 < 4; ++c4) {
            const int idx = wave * 4 + c4;
            const int pl = idx & 1, c = idx >> 1;
            const size_t gb = (size_t)(nb0 + c * 16 + (lane >> 2)) * DIM + k0 + sgB * 8;
            if (pl) { GLDS16(WoloT + gb, &BlS[c * 512]); }
            else    { GLDS16(WohiT + gb, &BhS[c * 512]); }
        }
        bf16x8 eh[2], el[2];
        #pragma unroll
        for (int m = 0; m < 2; ++m) {
            const size_t ra = (size_t)(m * 16 + fr) * DIM + k0 + q * 8;
            eh[m] = *(const bf16x8*)&embH[ra];
            el[m] = *(const bf16x8*)&embL[ra];
        }
        __syncthreads();
        bf16x8 bh[2], bl[2];
        #pragma unroll
        for (int j = 0; j < 2; ++j) {
            bh[j] = *(const bf16x8*)&BhS[crow0 + j * 512 + fswzB];
            bl[j] = *(const bf16x8*)&BlS[crow0 + j * 512 + fswzB];
        }
        #pragma unroll
        for (int m = 0; m < 2; ++m)
            #pragma unroll
            for (int j = 0; j < 2; ++j) {
                acc[m][j] = __builtin_amdgcn_mfma_f32_16x16x32_bf16(eh[m], bh[j], acc[m][j], 0, 0, 0);
                acc[m][j] = __builtin_amdgcn_mfma_f32_16x16x32_bf16(eh[m], bl[j], acc[m][j], 0, 0, 0);
                acc[m][j] = __builtin_amdgcn_mfma_f32_16x16x32_bf16(el[m], bh[j], acc[m][j], 0, 0, 0);
            }
        __syncthreads();
    }
    #pragma unroll
    for (int m = 0; m < 2; ++m) {
        const int row = m * 16 + q * 4;
        #pragma unroll
        for (int j = 0; j < 2; ++j) {
            const int col = nb0 + wave * 32 + j * 16 + fr;
            const float bb = TANH_SCALE * Wo_b[col];
            #pragma unroll
            for (int r = 0; r < 4; ++r)
                w_o[(size_t)(row + r) * DIM + col] = acc[m][j][r] + bb;
        }
    }
}

// ---------------- k_gemm_e: w_v tile via split-bf16 MFMA (never written to HBM), then
// fused k_e epilogue: partial[nb][(b*32+ch)*512+l] = sum_{d in block} we_d*sig(wo+wv).
__global__ __launch_bounds__(256) void k_gemm_e(
    const float* __restrict__ A,
    const ushort* __restrict__ Bhi, const ushort* __restrict__ Blo,
    const float* __restrict__ bias,
    const float* __restrict__ w_o, const float* __restrict__ We_w,
    float* __restrict__ partial)
{
    __shared__ __align__(16) char smem[65536];
    float*  AfS = (float*)smem;             // main loop: 32 KB (2 bufs)
    ushort* BhS = (ushort*)(smem + 32768);  // 16 KB
    ushort* BlS = (ushort*)(smem + 49152);  // 16 KB
    float*  woS = (float*)smem;             // epilogue: [32][128] = 16 KB
    float*  wvS = (float*)(smem + 16384);   // epilogue: [64][132] = 33.8 KB

    const int bid = blockIdx.x;
    const int t = threadIdx.x;
    const int wave = t >> 6, lane = t & 63;

    const int sgB = (lane & 3) ^ ((lane >> 3) & 3);
    const int sgA = (lane & 7) ^ ((lane >> 3) & 7);
    const int fr = lane & 15;
    const int q  = lane >> 4;
    const int fswzB = (q ^ ((fr >> 1) & 3)) * 8;

    const int mb = (bid & 7) * 16 + (bid >> 5);   // XCD-chunked
    const int nb = (bid >> 3) & 3;
    const int bm = mb * 128, bn = nb * 128;
    const int wm = wave >> 1, wn = wave & 1;
    const int brow0 = (wn * 64 + fr) * 32;
    const int pA0 = (2 * q) ^ (fr & 7);
    const int pA1 = (2 * q + 1) ^ (fr & 7);

    f32x4 acc[4][4] = {};

    auto stage = [&](int p, int k0) {
        #pragma unroll
        for (int c4 = 0; c4 < 4; ++c4) {
            const int ca = wave * 4 + c4;
            const size_t ga = (size_t)(bm + ca * 8 + (lane >> 3)) * DIM + k0 + sgA * 4;
            GLDS16(A + ga, &AfS[p * 4096 + ca * 256]);
            const int pl = ca & 1, cb = ca >> 1;
            const size_t gb = (size_t)(bn + cb * 16 + (lane >> 2)) * DIM + k0 + sgB * 8;
            if (pl) { GLDS16(Blo + gb, &BlS[p * 4096 + cb * 512]); }
            else    { GLDS16(Bhi + gb, &BhS[p * 4096 + cb * 512]); }
        }
    };

    stage(0, 0);
    __syncthreads();
    int cur = 0;
    for (int ks = 0; ks < 16; ++ks) {
        if (ks < 15) stage(cur ^ 1, (ks + 1) * 32);
        const int co = cur * 4096;
        bf16x8 ah[4], al[4], bh[4], bl[4];
        #pragma unroll
        for (int i = 0; i < 4; ++i) {
            const float* arow = &AfS[co + (wm * 64 + i * 16 + fr) * 32];
            float4 fa = *(const float4*)&arow[pA0 * 4];
            float4 fb = *(const float4*)&arow[pA1 * 4];
            union { unsigned u[4]; bf16x8 v; } H, L;
            split2u(fa.x, fa.y, H.u[0], L.u[0]);
            split2u(fa.z, fa.w, H.u[1], L.u[1]);
            split2u(fb.x, fb.y, H.u[2], L.u[2]);
            split2u(fb.z, fb.w, H.u[3], L.u[3]);
            ah[i] = H.v; al[i] = L.v;
            bh[i] = *(const bf16x8*)&BhS[co + brow0 + i * 512 + fswzB];
            bl[i] = *(const bf16x8*)&BlS[co + brow0 + i * 512 + fswzB];
        }
        #pragma unroll
        for (int i = 0; i < 4; ++i)
            #pragma unroll
            for (int j = 0; j < 4; ++j) {
                acc[i][j] = __builtin_amdgcn_mfma_f32_16x16x32_bf16(ah[i], bh[j], acc[i][j], 0, 0, 0);
                acc[i][j] = __builtin_amdgcn_mfma_f32_16x16x32_bf16(ah[i], bl[j], acc[i][j], 0, 0, 0);
                acc[i][j] = __builtin_amdgcn_mfma_f32_16x16x32_bf16(al[i], bh[j], acc[i][j], 0, 0, 0);
            }
        __syncthreads();
        cur ^= 1;
    }

    // ---------------- fused k_e epilogue ----------------
    // stage wo slice [32 ch][128 d] (cols bn..bn+127) into woS via GLDS (linear)
    #pragma unroll
    for (int cc = 0; cc < 4; ++cc) {
        const int flat = cc * 256 + t;                 // 16B chunk id
        const float* src = w_o + (size_t)(flat >> 5) * DIM + bn + ((flat & 31) << 2);
        GLDS16(src, &woS[cc * 1024 + wave * 256]);
    }

    const float4* weP = (const float4*)(We_w + bn);
    const float4 we0 = weP[fr];
    const float4 we1 = weP[16 + fr];
    float bb[4];
    #pragma unroll
    for (int jj = 0; jj < 4; ++jj)
        bb[jj] = TANH_SCALE * bias[bn + wn * 64 + jj * 16 + fr];

    const int b  = mb >> 2;
    const int lb = (mb & 3) * 128;
    float* part = partial + (size_t)nb * (BS * NCH * LSEQ);

    #pragma unroll
    for (int h = 0; h < 2; ++h) {
        __syncthreads();   // h=0: woS staged + LDS reuse safe; h=1: chunk0 compute done
        if (wm == h) {
            #pragma unroll
            for (int i = 0; i < 4; ++i)
                #pragma unroll
                for (int jj = 0; jj < 4; ++jj)
                    #pragma unroll
                    for (int r = 0; r < 4; ++r)
                        wvS[(i * 16 + q * 4 + r) * 132 + wn * 64 + jj * 16 + fr] =
                            acc[i][jj][r] + bb[jj];
        }
        __syncthreads();
        for (int lp = 0; lp < 4; ++lp) {
            const int lloc = wave * 16 + lp * 4 + q;
            const float4* wvp4 = (const float4*)&wvS[lloc * 132];
            const float4 wv0 = wvp4[fr];
            const float4 wv1 = wvp4[16 + fr];
            float sv0[16], sv1[16];
            #pragma unroll 4
            for (int ch = 0; ch < 16; ++ch) {
                const float4* worow = (const float4*)&woS[ch * 128];
                sv0[ch] = sig4(worow[16 + fr], wv1, we1, sig4(worow[fr], wv0, we0, 0.0f));
            }
            #pragma unroll 4
            for (int ch = 0; ch < 16; ++ch) {
                const float4* worow = (const float4*)&woS[(16 + ch) * 128];
                sv1[ch] = sig4(worow[16 + fr], wv1, we1, sig4(worow[fr], wv0, we0, 0.0f));
            }
            const float res0 = tree16(sv0, fr);
            const float res1 = tree16(sv1, fr);
            const int lg = lb + h * 64 + lloc;
            part[(size_t)(b * NCH + fr) * LSEQ + lg]      = res0;
            part[(size_t)(b * NCH + 16 + fr) * LSEQ + lg] = res1;
        }
    }
}

// ---------------- k_soft: e = -2 * sum(partial[0..3]); softmax over l; split bf16 planes.
__global__ __launch_bounds__(256) void k_soft(
    const float* __restrict__ part, ushort* __restrict__ aH, ushort* __restrict__ aL)
{
    const int row = blockIdx.x * 4 + (threadIdx.x >> 6);
    const int lane = threadIdx.x & 63;
    const size_t off = (size_t)row * LSEQ;
    const size_t stride = (size_t)BS * NCH * LSEQ;
    const float4* p0 = (const float4*)(part + off);
    const float4* p1 = (const float4*)(part + stride + off);
    const float4* p2 = (const float4*)(part + 2 * stride + off);
    const float4* p3 = (const float4*)(part + 3 * stride + off);

    float4 a0 = p0[2 * lane], a1 = p1[2 * lane], a2 = p2[2 * lane], a3 = p3[2 * lane];
    float4 b0 = p0[2 * lane + 1], b1 = p1[2 * lane + 1], b2 = p2[2 * lane + 1], b3 = p3[2 * lane + 1];
    float4 v0, v1;
    v0.x = -2.0f * (((a0.x + a1.x) + (a2.x + a3.x)));
    v0.y = -2.0f * (((a0.y + a1.y) + (a2.y + a3.y)));
    v0.z = -2.0f * (((a0.z + a1.z) + (a2.z + a3.z)));
    v0.w = -2.0f * (((a0.w + a1.w) + (a2.w + a3.w)));
    v1.x = -2.0f * (((b0.x + b1.x) + (b2.x + b3.x)));
    v1.y = -2.0f * (((b0.y + b1.y) + (b2.y + b3.y)));
    v1.z = -2.0f * (((b0.z + b1.z) + (b2.z + b3.z)));
    v1.w = -2.0f * (((b0.w + b1.w) + (b2.w + b3.w)));

    float m = fmaxf(fmaxf(fmaxf(v0.x, v0.y), fmaxf(v0.z, v0.w)),
                    fmaxf(fmaxf(v1.x, v1.y), fmaxf(v1.z, v1.w)));
    #pragma unroll
    for (int offx = 32; offx > 0; offx >>= 1) m = fmaxf(m, __shfl_xor(m, offx, 64));
    float p[8];
    p[0] = __expf(v0.x - m); p[1] = __expf(v0.y - m);
    p[2] = __expf(v0.z - m); p[3] = __expf(v0.w - m);
    p[4] = __expf(v1.x - m); p[5] = __expf(v1.y - m);
    p[6] = __expf(v1.z - m); p[7] = __expf(v1.w - m);
    float s = ((p[0] + p[1]) + (p[2] + p[3])) + ((p[4] + p[5]) + (p[6] + p[7]));
    #pragma unroll
    for (int offx = 32; offx > 0; offx >>= 1) s += __shfl_xor(s, offx, 64);
    const float inv = 1.0f / s;
    unsigned h01, l01, h23, l23, h45, l45, h67, l67;
    split2u(p[0] * inv, p[1] * inv, h01, l01);
    split2u(p[2] * inv, p[3] * inv, h23, l23);
    split2u(p[4] * inv, p[5] * inv, h45, l45);
    split2u(p[6] * inv, p[7] * inv, h67, l67);
    uint2* oh = (uint2*)(aH + (size_t)row * LSEQ);
    uint2* ol = (uint2*)(aL + (size_t)row * LSEQ);
    oh[2 * lane]     = make_uint2(h01, h23);
    oh[2 * lane + 1] = make_uint2(h45, h67);
    ol[2 * lane]     = make_uint2(l01, l23);
    ol[2 * lane + 1] = make_uint2(l45, l67);
}

// ---------------- k_vf: vf(n,d) = sum_l alpha(n,l) inp(l,d); barrier-free per-wave pipeline.
__global__ __launch_bounds__(256) void k_vf(
    const float* __restrict__ inp,
    const ushort* __restrict__ aH, const ushort* __restrict__ aL,
    float* __restrict__ part)
{
    __shared__ unsigned T[4][16 * 68];
    const int dgrp = blockIdx.x >> 1, ls = blockIdx.x & 1;
    const int b = blockIdx.y;
    const int t = threadIdx.x, wave = t >> 6, lane = t & 63;
    const int d0 = (dgrp * 4 + wave) * 16;
    const int lbase = ls * 256;
    const int c = lane & 15, g = lane >> 4;

    unsigned* Tw = T[wave];
    const ushort* aHb = aH + (size_t)b * NCH * LSEQ;
    const ushort* aLb = aL + (size_t)b * NCH * LSEQ;

    f32x4 acc0 = {}, acc1 = {};

    for (int l0 = 0; l0 < 256; l0 += 64) {
        const float4* src = (const float4*)(inp + ((size_t)(b * LSEQ) + lbase + l0 + lane) * DIM + d0);
        float4 v0 = src[0], v1 = src[1], v2 = src[2], v3 = src[3];
        unsigned ev[16];
        {
            unsigned hp, lp;
            split2u(v0.x, v0.y, hp, lp); ev[0] = (lp << 16) | (hp & 0xFFFFu); ev[1] = (lp & 0xFFFF0000u) | (hp >> 16);
            split2u(v0.z, v0.w, hp, lp); ev[2] = (lp << 16) | (hp & 0xFFFFu); ev[3] = (lp & 0xFFFF0000u) | (hp >> 16);
            split2u(v1.x, v1.y, hp, lp); ev[4] = (lp << 16) | (hp & 0xFFFFu); ev[5] = (lp & 0xFFFF0000u) | (hp >> 16);
            split2u(v1.z, v1.w, hp, lp); ev[6] = (lp << 16) | (hp & 0xFFFFu); ev[7] = (lp & 0xFFFF0000u) | (hp >> 16);
            split2u(v2.x, v2.y, hp, lp); ev[8] = (lp << 16) | (hp & 0xFFFFu); ev[9] = (lp & 0xFFFF0000u) | (hp >> 16);
            split2u(v2.z, v2.w, hp, lp); ev[10] = (lp << 16) | (hp & 0xFFFFu); ev[11] = (lp & 0xFFFF0000u) | (hp >> 16);
            split2u(v3.x, v3.y, hp, lp); ev[12] = (lp << 16) | (hp & 0xFFFFu); ev[13] = (lp & 0xFFFF0000u) | (hp >> 16);
            split2u(v3.z, v3.w, hp, lp); ev[14] = (lp << 16) | (hp & 0xFFFFu); ev[15] = (lp & 0xFFFF0000u) | (hp >> 16);
        }
        #pragma unroll
        for (int i = 0; i < 16; ++i)
            Tw[i * 68 + lane] = ev[i];
        #pragma unroll
        for (int ks = 0; ks < 2; ++ks) {
            const unsigned* bp = &Tw[c * 68 + ks * 32 + g * 8];
            uint4 w0 = *(const uint4*)bp;
            uint4 w1 = *(const uint4*)(bp + 4);
            union { unsigned u[4]; bf16x8 v; } H, L;
            H.u[0] = (w0.x & 0xFFFFu) | (w0.y << 16);
            H.u[1] = (w0.z & 0xFFFFu) | (w0.w << 16);
            H.u[2] = (w1.x & 0xFFFFu) | (w1.y << 16);
            H.u[3] = (w1.z & 0xFFFFu) | (w1.w << 16);
            L.u[0] = (w0.x >> 16) | (w0.y & 0xFFFF0000u);
            L.u[1] = (w0.z >> 16) | (w0.w & 0xFFFF0000u);
            L.u[2] = (w1.x >> 16) | (w1.y & 0xFFFF0000u);
            L.u[3] = (w1.z >> 16) | (w1.w & 0xFFFF0000u);

            const int lfrag = lbase + l0 + ks * 32 + g * 8;
            bf16x8 a0h = *(const bf16x8*)&aHb[(size_t)c * LSEQ + lfrag];
            bf16x8 a0l = *(const bf16x8*)&aLb[(size_t)c * LSEQ + lfrag];
            bf16x8 a1h = *(const bf16x8*)&aHb[(size_t)(16 + c) * LSEQ + lfrag];
            bf16x8 a1l = *(const bf16x8*)&aLb[(size_t)(16 + c) * LSEQ + lfrag];

            acc0 = __builtin_amdgcn_mfma_f32_16x16x32_bf16(a0h, H.v, acc0, 0, 0, 0);
            acc0 = __builtin_amdgcn_mfma_f32_16x16x32_bf16(a0h, L.v, acc0, 0, 0, 0);
            acc0 = __builtin_amdgcn_mfma_f32_16x16x32_bf16(a0l, H.v, acc0, 0, 0, 0);
            acc1 = __builtin_amdgcn_mfma_f32_16x16x32_bf16(a1h, H.v, acc1, 0, 0, 0);
            acc1 = __builtin_amdgcn_mfma_f32_16x16x32_bf16(a1h, L.v, acc1, 0, 0, 0);
            acc1 = __builtin_amdgcn_mfma_f32_16x16x32_bf16(a1l, H.v, acc1, 0, 0, 0);
        }
    }

    const size_t base = (size_t)(ls * BS * NCH + b * NCH) * DIM + d0 + c;
    #pragma unroll
    for (int r = 0; r < 4; ++r) {
        part[base + (size_t)(g * 4 + r) * DIM]        = acc0[r];
        part[base + (size_t)(16 + g * 4 + r) * DIM]   = acc1[r];
    }
}

// ---------------- k_lg: vf = part0+part1 (to d_out) + logits. 4 rows, 256 blocks.
__global__ __launch_bounds__(256) void k_lg(
    const float* __restrict__ part, const float* __restrict__ Wc_w,
    const float* __restrict__ Wc_b, float* __restrict__ out_vf,
    float* __restrict__ out_logits)
{
    __shared__ float vfS[4][DIM];
    __shared__ float lgS[2][4][NDICT];
    const int r0 = blockIdx.x * 4;
    const int t = threadIdx.x;
    const int wave = t >> 6, lane = t & 63;

    const float2* p0 = (const float2*)(part + (size_t)(r0 + wave) * DIM);
    const float2* p1 = (const float2*)(part + (size_t)(BS * NCH + r0 + wave) * DIM);
    float2* vout = (float2*)(out_vf + (size_t)(r0 + wave) * DIM);
    #pragma unroll
    for (int qq = 0; qq < 4; ++qq) {
        float2 x = p0[lane + 64 * qq], y = p1[lane + 64 * qq];
        float2 z; z.x = x.x + y.x; z.y = x.y + y.y;
        ((float2*)&vfS[wave][0])[lane + 64 * qq] = z;
        vout[lane + 64 * qq] = z;
    }
    __syncthreads();

    const int j = t & 127, half = t >> 7;
    if (j < NDICT) {
        const float* wc = Wc_w + (size_t)half * 256 * NDICT + j;
        const float* v0 = &vfS[0][half * 256];
        const float* v1 = &vfS[1][half * 256];
        const float* v2 = &vfS[2][half * 256];
        const float* v3 = &vfS[3][half * 256];
        float a0 = 0.f, a1 = 0.f, a2 = 0.f, a3 = 0.f;
        #pragma unroll 4
        for (int d = 0; d < 256; ++d) {
            float w = wc[(size_t)d * NDICT];
            a0 = fmaf(v0[d], w, a0); a1 = fmaf(v1[d], w, a1);
            a2 = fmaf(v2[d], w, a2); a3 = fmaf(v3[d], w, a3);
        }
        lgS[half][0][j] = a0; lgS[half][1][j] = a1;
        lgS[half][2][j] = a2; lgS[half][3][j] = a3;
    }
    __syncthreads();
    for (int idx = t; idx < 4 * NDICT; idx += 256) {
        const int r = idx / NDICT, jj = idx - r * NDICT;
        out_logits[(size_t)(r0 + r) * NDICT + jj] = Wc_b[jj] + lgS[0][r][jj] + lgS[1][r][jj];
    }
}

extern "C" void kernel_launch(void* const* d_in, const int* in_sizes, int n_in,
                              void* d_out, int out_size, void* d_ws, size_t ws_size,
                              hipStream_t stream)
{
    const float* inp  = (const float*)d_in[0];
    const float* emb  = (const float*)d_in[1];
    const float* Wo_w = (const float*)d_in[2];
    const float* Wo_b = (const float*)d_in[3];
    const float* Wv_w = (const float*)d_in[4];
    const float* Wv_b = (const float*)d_in[5];
    const float* We_w = (const float*)d_in[6];
    // d_in[7] = We_b: unused (softmax shift-invariant; e not an output)
    const float* Wc_w = (const float*)d_in[8];
    const float* Wc_b = (const float*)d_in[9];

    char* p = (char*)d_ws;
    float*  w_o   = (float*)p;  p += (64 << 10);
    ushort* BhiT  = (ushort*)p; p += (size_t)DIM * DIM * 2;            // 512 KB
    ushort* BloT  = (ushort*)p; p += (size_t)DIM * DIM * 2;
    ushort* WohiT = (ushort*)p; p += (size_t)DIM * DIM * 2;
    ushort* WoloT = (ushort*)p; p += (size_t)DIM * DIM * 2;
    ushort* embH  = (ushort*)p; p += (size_t)NCH * DIM * 2;            // 32 KB
    ushort* embL  = (ushort*)p; p += (size_t)NCH * DIM * 2;
    ushort* aH    = (ushort*)p; p += (size_t)BS * NCH * LSEQ * 2;      // 1 MB
    ushort* aL    = (ushort*)p; p += (size_t)BS * NCH * LSEQ * 2;
    float*  partV = (float*)p;  p += (size_t)2 * BS * NCH * DIM * 4;   // 4 MB
    float*  partE = (float*)p;  p += (size_t)4 * BS * NCH * LSEQ * 4;  // 8 MB

    float* out_vf = (float*)d_out;
    float* out_lg = out_vf + BS * NCH * DIM;

    k_prep<<<dim3(129), dim3(256), 0, stream>>>(Wv_w, BhiT, BloT, Wo_w, WohiT, WoloT,
                                                emb, embH, embL);
    k_wo<<<dim3(4), dim3(256), 0, stream>>>(WohiT, WoloT, embH, embL, Wo_b, w_o);
    k_gemm_e<<<dim3(512), dim3(256), 0, stream>>>(inp, BhiT, BloT, Wv_b, w_o, We_w, partE);
    k_soft<<<dim3(256), dim3(256), 0, stream>>>(partE, aH, aL);
    k_vf<<<dim3(16, BS), dim3(256), 0, stream>>>(inp, aH, aL, partV);
    k_lg<<<dim3(256), dim3(256), 0, stream>>>(partV, Wc_w, Wc_b, out_vf, out_lg);
}

// Round 15
// 143.401 us; speedup vs baseline: 1.0915x; 1.0915x over previous
//
#include <hip/hip_runtime.h>
#include <hip/hip_bf16.h>

#define BS    32
#define LSEQ  512
#define DIM   512
#define NCH   32
#define NDICT 97
#define CHB   16

// 2*log2(e): tanh(x) = 1 - 2*sigmoid(-2x); sigmoid(-2x) = 1/(1+2^(x*2*log2e))
#define TANH_SCALE 2.8853900817779268f

typedef __attribute__((ext_vector_type(8))) short bf16x8;
typedef __attribute__((ext_vector_type(4))) float f32x4;

#define GLDS16(gsrc, ldst) \
  __builtin_amdgcn_global_load_lds((const __attribute__((address_space(1))) void*)(gsrc), \
                                   (__attribute__((address_space(3))) void*)(ldst), 16, 0, 0)

__device__ __forceinline__ float sig_from_scaled(float xs) {
    float e2 = __builtin_amdgcn_exp2f(xs);
    return __builtin_amdgcn_rcpf(1.0f + e2);
}

// split two fp32 into packed bf16 hi-pair / lo-pair (elem0 in low 16).
__device__ __forceinline__ void split2u(float x0, float x1, unsigned& hp, unsigned& lp) {
    unsigned r0 = __float_as_uint(x0) + 0x8000u;
    unsigned r1 = __float_as_uint(x1) + 0x8000u;
    float f0 = __uint_as_float(r0 & 0xFFFF0000u);
    float f1 = __uint_as_float(r1 & 0xFFFF0000u);
    hp = (r0 >> 16) | (r1 & 0xFFFF0000u);
    unsigned s0 = __float_as_uint(x0 - f0);
    unsigned s1 = __float_as_uint(x1 - f1);
    lp = (s0 >> 16) | (s1 & 0xFFFF0000u);
}

// ---------------- k_prep (weights only): blocks 0..63: Wv*SCALE -> B^T hi/lo;
//                  64..127: Wo*SCALE -> Wo^T hi/lo; block 128: emb -> hi/lo planes.
__global__ __launch_bounds__(256) void k_prep(
    const float* __restrict__ Wv, ushort* __restrict__ BhiT, ushort* __restrict__ BloT,
    const float* __restrict__ Wo, ushort* __restrict__ WohiT, ushort* __restrict__ WoloT,
    const float* __restrict__ emb, ushort* __restrict__ embH, ushort* __restrict__ embL)
{
    __shared__ float tile[64][65];
    const int bid = blockIdx.x;
    const int t = threadIdx.x;
    if (bid < 128) {
        const bool isWv = bid < 64;
        const float* src = isWv ? Wv : Wo;
        ushort* dH = isWv ? BhiT : WohiT;
        ushort* dL = isWv ? BloT : WoloT;
        const int bb = bid & 63;
        const int k0 = (bb >> 3) * 64, n0 = (bb & 7) * 64;
        const int tr = t >> 4, tc = (t & 15) * 4;
        #pragma unroll
        for (int rr = 0; rr < 64; rr += 16) {
            float4 v = *(const float4*)&src[(size_t)(k0 + rr + tr) * DIM + n0 + tc];
            tile[rr + tr][tc + 0] = v.x; tile[rr + tr][tc + 1] = v.y;
            tile[rr + tr][tc + 2] = v.z; tile[rr + tr][tc + 3] = v.w;
        }
        __syncthreads();
        #pragma unroll
        for (int rr = 0; rr < 64; rr += 16) {
            const int n = rr + tr;
            unsigned h01, l01, h23, l23;
            split2u(tile[tc + 0][n] * TANH_SCALE, tile[tc + 1][n] * TANH_SCALE, h01, l01);
            split2u(tile[tc + 2][n] * TANH_SCALE, tile[tc + 3][n] * TANH_SCALE, h23, l23);
            *(uint2*)&dH[(size_t)(n0 + n) * DIM + k0 + tc] = make_uint2(h01, h23);
            *(uint2*)&dL[(size_t)(n0 + n) * DIM + k0 + tc] = make_uint2(l01, l23);
        }
    } else {
        for (int i = t; i < 4096; i += 256) {
            float4 v = ((const float4*)emb)[i];
            unsigned h01, l01, h23, l23;
            split2u(v.x, v.y, h01, l01);
            split2u(v.z, v.w, h23, l23);
            ((uint2*)embH)[i] = make_uint2(h01, h23);
            ((uint2*)embL)[i] = make_uint2(l01, l23);
        }
    }
}

// ---------------- k_gemm v4 (R11/R13, measured net-best): A = fp32 inp staged via
// global_load_lds (granule XOR swizzle) + in-register split; B = pre-split planes.
// BM=BN=128, BK=32, double-buffered, 64 KB LDS. blocks 0..511: w_v; 512..515: w_o.
__global__ __launch_bounds__(256) void k_gemm(
    const float* __restrict__ A,
    const ushort* __restrict__ Bhi, const ushort* __restrict__ Blo,
    const float* __restrict__ bias, float* __restrict__ C,
    const ushort* __restrict__ WohiT, const ushort* __restrict__ WoloT,
    const ushort* __restrict__ embH, const ushort* __restrict__ embL,
    const float* __restrict__ Wo_b, float* __restrict__ w_o)
{
    __shared__ float  AfS[2 * 128 * 32];   // 16 KB per buf (fp32 A tile)
    __shared__ ushort BhS[2 * 128 * 32];   // 8 KB per buf
    __shared__ ushort BlS[2 * 128 * 32];   // 8 KB per buf

    const int bid = blockIdx.x;
    const int t = threadIdx.x;
    const int wave = t >> 6, lane = t & 63;

    const int sgB = (lane & 3) ^ ((lane >> 3) & 3);
    const int sgA = (lane & 7) ^ ((lane >> 3) & 7);

    const int fr   = lane & 15;
    const int q    = lane >> 4;
    const int fswzB = (q ^ ((fr >> 1) & 3)) * 8;

    if (bid < 512) {
        const int mb = (bid & 7) * 16 + (bid >> 5);   // XCD-chunked
        const int nb = (bid >> 3) & 3;
        const int bm = mb * 128, bn = nb * 128;
        const int wm = wave >> 1, wn = wave & 1;
        const int brow0 = (wn * 64 + fr) * 32;
        const int pA0 = (2 * q) ^ (fr & 7);
        const int pA1 = (2 * q + 1) ^ (fr & 7);

        f32x4 acc[4][4] = {};

        auto stage = [&](int p, int k0) {
            #pragma unroll
            for (int c4 = 0; c4 < 4; ++c4) {
                const int ca = wave * 4 + c4;
                const size_t ga = (size_t)(bm + ca * 8 + (lane >> 3)) * DIM + k0 + sgA * 4;
                GLDS16(A + ga, &AfS[p * 4096 + ca * 256]);
                const int idx = wave * 4 + c4;
                const int pl = idx & 1, cb = idx >> 1;
                const size_t gb = (size_t)(bn + cb * 16 + (lane >> 2)) * DIM + k0 + sgB * 8;
                if (pl) { GLDS16(Blo + gb, &BlS[p * 4096 + cb * 512]); }
                else    { GLDS16(Bhi + gb, &BhS[p * 4096 + cb * 512]); }
            }
        };

        stage(0, 0);
        __syncthreads();
        int cur = 0;
        for (int ks = 0; ks < 16; ++ks) {
            if (ks < 15) stage(cur ^ 1, (ks + 1) * 32);
            const int co = cur * 4096;
            bf16x8 ah[4], al[4], bh[4], bl[4];
            #pragma unroll
            for (int i = 0; i < 4; ++i) {
                const float* arow = &AfS[co + (wm * 64 + i * 16 + fr) * 32];
                float4 fa = *(const float4*)&arow[pA0 * 4];
                float4 fb = *(const float4*)&arow[pA1 * 4];
                union { unsigned u[4]; bf16x8 v; } H, L;
                split2u(fa.x, fa.y, H.u[0], L.u[0]);
                split2u(fa.z, fa.w, H.u[1], L.u[1]);
                split2u(fb.x, fb.y, H.u[2], L.u[2]);
                split2u(fb.z, fb.w, H.u[3], L.u[3]);
                ah[i] = H.v; al[i] = L.v;
                bh[i] = *(const bf16x8*)&BhS[co + brow0 + i * 512 + fswzB];
                bl[i] = *(const bf16x8*)&BlS[co + brow0 + i * 512 + fswzB];
            }
            #pragma unroll
            for (int i = 0; i < 4; ++i)
                #pragma unroll
                for (int j = 0; j < 4; ++j) {
                    acc[i][j] = __builtin_amdgcn_mfma_f32_16x16x32_bf16(ah[i], bh[j], acc[i][j], 0, 0, 0);
                    acc[i][j] = __builtin_amdgcn_mfma_f32_16x16x32_bf16(ah[i], bl[j], acc[i][j], 0, 0, 0);
                    acc[i][j] = __builtin_amdgcn_mfma_f32_16x16x32_bf16(al[i], bh[j], acc[i][j], 0, 0, 0);
                }
            __syncthreads();
            cur ^= 1;
        }

        #pragma unroll
        for (int i = 0; i < 4; ++i) {
            const int m = bm + wm * 64 + i * 16 + q * 4;
            #pragma unroll
            for (int j = 0; j < 4; ++j) {
                const int n = bn + wn * 64 + j * 16 + fr;
                const float bb = TANH_SCALE * bias[n];
                #pragma unroll
                for (int r = 0; r < 4; ++r)
                    C[(size_t)(m + r) * DIM + n] = acc[i][j][r] + bb;
            }
        }
    } else {
        // w_o: M=32, N=128 per block (4 blocks). A = emb planes reg-direct; B = Wo^T staged.
        const int nb0 = (bid - 512) * 128;
        const int crow0 = (wave * 32 + fr) * 32;
        f32x4 acc[2][2] = {};

        for (int k0 = 0; k0 < DIM; k0 += 32) {
            #pragma unroll
            for (int c4 = 0; c4 < 4; ++c4) {
                const int idx = wave * 4 + c4;
                const int pl = idx & 1, c = idx >> 1;
                const size_t gb = (size_t)(nb0 + c * 16 + (lane >> 2)) * DIM + k0 + sgB * 8;
                if (pl) { GLDS16(WoloT + gb, &BlS[c * 512]); }
                else    { GLDS16(WohiT + gb, &BhS[c * 512]); }
            }
            bf16x8 eh[2], el[2];
            #pragma unroll
            for (int m = 0; m < 2; ++m) {
                const size_t ra = (size_t)(m * 16 + fr) * DIM + k0 + q * 8;
                eh[m] = *(const bf16x8*)&embH[ra];
                el[m] = *(const bf16x8*)&embL[ra];
            }
            __syncthreads();

            bf16x8 bh[2], bl[2];
            #pragma unroll
            for (int j = 0; j < 2; ++j) {
                bh[j] = *(const bf16x8*)&BhS[crow0 + j * 512 + fswzB];
                bl[j] = *(const bf16x8*)&BlS[crow0 + j * 512 + fswzB];
            }
            #pragma unroll
            for (int m = 0; m < 2; ++m)
                #pragma unroll
                for (int j = 0; j < 2; ++j) {
                    acc[m][j] = __builtin_amdgcn_mfma_f32_16x16x32_bf16(eh[m], bh[j], acc[m][j], 0, 0, 0);
                    acc[m][j] = __builtin_amdgcn_mfma_f32_16x16x32_bf16(eh[m], bl[j], acc[m][j], 0, 0, 0);
                    acc[m][j] = __builtin_amdgcn_mfma_f32_16x16x32_bf16(el[m], bh[j], acc[m][j], 0, 0, 0);
                }
            __syncthreads();
        }

        #pragma unroll
        for (int m = 0; m < 2; ++m) {
            const int row = m * 16 + q * 4;
            #pragma unroll
            for (int j = 0; j < 2; ++j) {
                const int col = nb0 + wave * 32 + j * 16 + fr;
                const float bb = TANH_SCALE * Wo_b[col];
                #pragma unroll
                for (int r = 0; r < 4; ++r)
                    w_o[(size_t)(row + r) * DIM + col] = acc[m][j][r] + bb;
            }
        }
    }
}

// ---------------- k_e: e[b,n,l] = Wsum - 2 * sum_d we_d * sigmoid-form  (w_v pre-scaled)
// ROUND-8 WINNER CONFIG: 256 thr, launch_bounds(256,4), VGPR 64. Do not touch.
__global__ __launch_bounds__(256, 4) void k_e(
    const float* __restrict__ w_v, const float* __restrict__ w_o,
    const float* __restrict__ We_w, float* __restrict__ e)
{
    __shared__ float4 woS[CHB * 128];  // 32 KB
    const int lblk = blockIdx.x;
    const int b    = blockIdx.y;
    const int ch0  = blockIdx.z * CHB;
    const int t    = threadIdx.x;

    const float4* wog = ((const float4*)w_o) + ch0 * (DIM / 4);
    #pragma unroll
    for (int i = 0; i < CHB * 128 / 256; ++i)
        woS[t + 256 * i] = wog[t + 256 * i];

    const int wave = t >> 6, lane = t & 63;
    const int g = lane >> 4, j = lane & 15;
    const int l = lblk * 16 + wave * 4 + g;

    const float4* wvp = (const float4*)(w_v + (size_t)(b * LSEQ + l) * DIM);
    const float4* wep = (const float4*)We_w;
    float4 wv[8], we[8];
    #pragma unroll
    for (int k = 0; k < 8; ++k) {
        wv[k] = wvp[16 * k + j];
        we[k] = wep[16 * k + j];
    }
    float wsum = 0.0f;
    #pragma unroll
    for (int k = 0; k < 8; ++k)
        wsum += (we[k].x + we[k].y) + (we[k].z + we[k].w);
    #pragma unroll
    for (int off = 1; off < 16; off <<= 1) wsum += __shfl_xor(wsum, off, 64);

    __syncthreads();

    float sv[CHB];
    #pragma unroll 4
    for (int i = 0; i < CHB; ++i) {
        const float4* wrow = &woS[i * 128];
        float s0 = 0.f, s1 = 0.f, s2 = 0.f, s3 = 0.f;
        #pragma unroll
        for (int k = 0; k < 8; ++k) {
            float4 wo4 = wrow[16 * k + j];
            s0 = fmaf(we[k].x, sig_from_scaled(wo4.x + wv[k].x), s0);
            s1 = fmaf(we[k].y, sig_from_scaled(wo4.y + wv[k].y), s1);
            s2 = fmaf(we[k].z, sig_from_scaled(wo4.z + wv[k].z), s2);
            s3 = fmaf(we[k].w, sig_from_scaled(wo4.w + wv[k].w), s3);
        }
        sv[i] = (s0 + s1) + (s2 + s3);
    }

    float t2[8];
    #pragma unroll
    for (int i = 0; i < 8; ++i) {
        float a = sv[2 * i]     + __shfl_xor(sv[2 * i],     1, 64);
        float c = sv[2 * i + 1] + __shfl_xor(sv[2 * i + 1], 1, 64);
        t2[i] = (j & 1) ? c : a;
    }
    float t4[4];
    #pragma unroll
    for (int i = 0; i < 4; ++i) {
        float a = t2[2 * i]     + __shfl_xor(t2[2 * i],     2, 64);
        float c = t2[2 * i + 1] + __shfl_xor(t2[2 * i + 1], 2, 64);
        t4[i] = (j & 2) ? c : a;
    }
    float t8[2];
    #pragma unroll
    for (int i = 0; i < 2; ++i) {
        float a = t4[2 * i]     + __shfl_xor(t4[2 * i],     4, 64);
        float c = t4[2 * i + 1] + __shfl_xor(t4[2 * i + 1], 4, 64);
        t8[i] = (j & 4) ? c : a;
    }
    float a = t8[0] + __shfl_xor(t8[0], 8, 64);
    float c = t8[1] + __shfl_xor(t8[1], 8, 64);
    float res = (j & 8) ? c : a;

    e[(size_t)(b * NCH + ch0 + j) * LSEQ + l] = fmaf(-2.0f, res, wsum);
}

// ---------------- k_soft: alpha = softmax(e) over l, split to bf16 hi/lo planes.
__global__ __launch_bounds__(256) void k_soft(
    const float* __restrict__ e, ushort* __restrict__ aH, ushort* __restrict__ aL)
{
    const int row = blockIdx.x * 4 + (threadIdx.x >> 6);
    const int lane = threadIdx.x & 63;
    const float4* erow = (const float4*)(e + (size_t)row * LSEQ);
    float4 v0 = erow[2 * lane], v1 = erow[2 * lane + 1];
    float m = fmaxf(fmaxf(fmaxf(v0.x, v0.y), fmaxf(v0.z, v0.w)),
                    fmaxf(fmaxf(v1.x, v1.y), fmaxf(v1.z, v1.w)));
    #pragma unroll
    for (int off = 32; off > 0; off >>= 1) m = fmaxf(m, __shfl_xor(m, off, 64));
    float p[8];
    p[0] = __expf(v0.x - m); p[1] = __expf(v0.y - m);
    p[2] = __expf(v0.z - m); p[3] = __expf(v0.w - m);
    p[4] = __expf(v1.x - m); p[5] = __expf(v1.y - m);
    p[6] = __expf(v1.z - m); p[7] = __expf(v1.w - m);
    float s = ((p[0] + p[1]) + (p[2] + p[3])) + ((p[4] + p[5]) + (p[6] + p[7]));
    #pragma unroll
    for (int off = 32; off > 0; off >>= 1) s += __shfl_xor(s, off, 64);
    const float inv = 1.0f / s;
    unsigned h01, l01, h23, l23, h45, l45, h67, l67;
    split2u(p[0] * inv, p[1] * inv, h01, l01);
    split2u(p[2] * inv, p[3] * inv, h23, l23);
    split2u(p[4] * inv, p[5] * inv, h45, l45);
    split2u(p[6] * inv, p[7] * inv, h67, l67);
    uint2* oh = (uint2*)(aH + (size_t)row * LSEQ);
    uint2* ol = (uint2*)(aL + (size_t)row * LSEQ);
    oh[2 * lane]     = make_uint2(h01, h23);
    oh[2 * lane + 1] = make_uint2(h45, h67);
    ol[2 * lane]     = make_uint2(l01, l23);
    ol[2 * lane + 1] = make_uint2(l45, l67);
}

// ---------------- k_vf: vf(n,d) = sum_l alpha(n,l) inp(l,d); barrier-free per-wave pipeline.
__global__ __launch_bounds__(256) void k_vf(
    const float* __restrict__ inp,
    const ushort* __restrict__ aH, const ushort* __restrict__ aL,
    float* __restrict__ part)
{
    __shared__ unsigned T[4][16 * 68];
    const int dgrp = blockIdx.x >> 1, ls = blockIdx.x & 1;
    const int b = blockIdx.y;
    const int t = threadIdx.x, wave = t >> 6, lane = t & 63;
    const int d0 = (dgrp * 4 + wave) * 16;
    const int lbase = ls * 256;
    const int c = lane & 15, g = lane >> 4;

    unsigned* Tw = T[wave];
    const ushort* aHb = aH + (size_t)b * NCH * LSEQ;
    const ushort* aLb = aL + (size_t)b * NCH * LSEQ;

    f32x4 acc0 = {}, acc1 = {};

    for (int l0 = 0; l0 < 256; l0 += 64) {
        const float4* src = (const float4*)(inp + ((size_t)(b * LSEQ) + lbase + l0 + lane) * DIM + d0);
        float4 v0 = src[0], v1 = src[1], v2 = src[2], v3 = src[3];
        unsigned ev[16];
        {
            unsigned hp, lp;
            split2u(v0.x, v0.y, hp, lp); ev[0] = (lp << 16) | (hp & 0xFFFFu); ev[1] = (lp & 0xFFFF0000u) | (hp >> 16);
            split2u(v0.z, v0.w, hp, lp); ev[2] = (lp << 16) | (hp & 0xFFFFu); ev[3] = (lp & 0xFFFF0000u) | (hp >> 16);
            split2u(v1.x, v1.y, hp, lp); ev[4] = (lp << 16) | (hp & 0xFFFFu); ev[5] = (lp & 0xFFFF0000u) | (hp >> 16);
            split2u(v1.z, v1.w, hp, lp); ev[6] = (lp << 16) | (hp & 0xFFFFu); ev[7] = (lp & 0xFFFF0000u) | (hp >> 16);
            split2u(v2.x, v2.y, hp, lp); ev[8] = (lp << 16) | (hp & 0xFFFFu); ev[9] = (lp & 0xFFFF0000u) | (hp >> 16);
            split2u(v2.z, v2.w, hp, lp); ev[10] = (lp << 16) | (hp & 0xFFFFu); ev[11] = (lp & 0xFFFF0000u) | (hp >> 16);
            split2u(v3.x, v3.y, hp, lp); ev[12] = (lp << 16) | (hp & 0xFFFFu); ev[13] = (lp & 0xFFFF0000u) | (hp >> 16);
            split2u(v3.z, v3.w, hp, lp); ev[14] = (lp << 16) | (hp & 0xFFFFu); ev[15] = (lp & 0xFFFF0000u) | (hp >> 16);
        }
        #pragma unroll
        for (int i = 0; i < 16; ++i)
            Tw[i * 68 + lane] = ev[i];
        #pragma unroll
        for (int ks = 0; ks < 2; ++ks) {
            const unsigned* bp = &Tw[c * 68 + ks * 32 + g * 8];
            uint4 w0 = *(const uint4*)bp;
            uint4 w1 = *(const uint4*)(bp + 4);
            union { unsigned u[4]; bf16x8 v; } H, L;
            H.u[0] = (w0.x & 0xFFFFu) | (w0.y << 16);
            H.u[1] = (w0.z & 0xFFFFu) | (w0.w << 16);
            H.u[2] = (w1.x & 0xFFFFu) | (w1.y << 16);
            H.u[3] = (w1.z & 0xFFFFu) | (w1.w << 16);
            L.u[0] = (w0.x >> 16) | (w0.y & 0xFFFF0000u);
            L.u[1] = (w0.z >> 16) | (w0.w & 0xFFFF0000u);
            L.u[2] = (w1.x >> 16) | (w1.y & 0xFFFF0000u);
            L.u[3] = (w1.z >> 16) | (w1.w & 0xFFFF0000u);

            const int lfrag = lbase + l0 + ks * 32 + g * 8;
            bf16x8 a0h = *(const bf16x8*)&aHb[(size_t)c * LSEQ + lfrag];
            bf16x8 a0l = *(const bf16x8*)&aLb[(size_t)c * LSEQ + lfrag];
            bf16x8 a1h = *(const bf16x8*)&aHb[(size_t)(16 + c) * LSEQ + lfrag];
            bf16x8 a1l = *(const bf16x8*)&aLb[(size_t)(16 + c) * LSEQ + lfrag];

            acc0 = __builtin_amdgcn_mfma_f32_16x16x32_bf16(a0h, H.v, acc0, 0, 0, 0);
            acc0 = __builtin_amdgcn_mfma_f32_16x16x32_bf16(a0h, L.v, acc0, 0, 0, 0);
            acc0 = __builtin_amdgcn_mfma_f32_16x16x32_bf16(a0l, H.v, acc0, 0, 0, 0);
            acc1 = __builtin_amdgcn_mfma_f32_16x16x32_bf16(a1h, H.v, acc1, 0, 0, 0);
            acc1 = __builtin_amdgcn_mfma_f32_16x16x32_bf16(a1h, L.v, acc1, 0, 0, 0);
            acc1 = __builtin_amdgcn_mfma_f32_16x16x32_bf16(a1l, H.v, acc1, 0, 0, 0);
        }
    }

    const size_t base = (size_t)(ls * BS * NCH + b * NCH) * DIM + d0 + c;
    #pragma unroll
    for (int r = 0; r < 4; ++r) {
        part[base + (size_t)(g * 4 + r) * DIM]        = acc0[r];
        part[base + (size_t)(16 + g * 4 + r) * DIM]   = acc1[r];
    }
}

// ---------------- k_lg (R10 winner): vf = part0+part1 (to d_out) + logits. 4 rows, 256 blocks.
__global__ __launch_bounds__(256) void k_lg(
    const float* __restrict__ part, const float* __restrict__ Wc_w,
    const float* __restrict__ Wc_b, float* __restrict__ out_vf,
    float* __restrict__ out_logits)
{
    __shared__ float vfS[4][DIM];
    __shared__ float lgS[2][4][NDICT];
    const int r0 = blockIdx.x * 4;
    const int t = threadIdx.x;
    const int wave = t >> 6, lane = t & 63;

    const float2* p0 = (const float2*)(part + (size_t)(r0 + wave) * DIM);
    const float2* p1 = (const float2*)(part + (size_t)(BS * NCH + r0 + wave) * DIM);
    float2* vout = (float2*)(out_vf + (size_t)(r0 + wave) * DIM);
    #pragma unroll
    for (int q = 0; q < 4; ++q) {
        float2 x = p0[lane + 64 * q], y = p1[lane + 64 * q];
        float2 z; z.x = x.x + y.x; z.y = x.y + y.y;
        ((float2*)&vfS[wave][0])[lane + 64 * q] = z;
        vout[lane + 64 * q] = z;
    }
    __syncthreads();

    const int j = t & 127, half = t >> 7;
    if (j < NDICT) {
        const float* wc = Wc_w + (size_t)half * 256 * NDICT + j;
        const float* v0 = &vfS[0][half * 256];
        const float* v1 = &vfS[1][half * 256];
        const float* v2 = &vfS[2][half * 256];
        const float* v3 = &vfS[3][half * 256];
        float a0 = 0.f, a1 = 0.f, a2 = 0.f, a3 = 0.f;
        #pragma unroll 4
        for (int d = 0; d < 256; ++d) {
            float w = wc[(size_t)d * NDICT];
            a0 = fmaf(v0[d], w, a0); a1 = fmaf(v1[d], w, a1);
            a2 = fmaf(v2[d], w, a2); a3 = fmaf(v3[d], w, a3);
        }
        lgS[half][0][j] = a0; lgS[half][1][j] = a1;
        lgS[half][2][j] = a2; lgS[half][3][j] = a3;
    }
    __syncthreads();
    for (int idx = t; idx < 4 * NDICT; idx += 256) {
        const int r = idx / NDICT, jj = idx - r * NDICT;
        out_logits[(size_t)(r0 + r) * NDICT + jj] = Wc_b[jj] + lgS[0][r][jj] + lgS[1][r][jj];
    }
}

extern "C" void kernel_launch(void* const* d_in, const int* in_sizes, int n_in,
                              void* d_out, int out_size, void* d_ws, size_t ws_size,
                              hipStream_t stream)
{
    const float* inp  = (const float*)d_in[0];
    const float* emb  = (const float*)d_in[1];
    const float* Wo_w = (const float*)d_in[2];
    const float* Wo_b = (const float*)d_in[3];
    const float* Wv_w = (const float*)d_in[4];
    const float* Wv_b = (const float*)d_in[5];
    const float* We_w = (const float*)d_in[6];
    // d_in[7] = We_b: unused (softmax shift-invariant; e not an output)
    const float* Wc_w = (const float*)d_in[8];
    const float* Wc_b = (const float*)d_in[9];

    char* p = (char*)d_ws;
    float*  w_o   = (float*)p;  p += (64 << 10);
    float*  ev    = (float*)p;  p += (size_t)BS * NCH * LSEQ * 4;      // 2 MB
    ushort* BhiT  = (ushort*)p; p += (size_t)DIM * DIM * 2;            // 512 KB
    ushort* BloT  = (ushort*)p; p += (size_t)DIM * DIM * 2;
    ushort* WohiT = (ushort*)p; p += (size_t)DIM * DIM * 2;
    ushort* WoloT = (ushort*)p; p += (size_t)DIM * DIM * 2;
    ushort* embH  = (ushort*)p; p += (size_t)NCH * DIM * 2;            // 32 KB
    ushort* embL  = (ushort*)p; p += (size_t)NCH * DIM * 2;
    ushort* aH    = (ushort*)p; p += (size_t)BS * NCH * LSEQ * 2;      // 1 MB
    ushort* aL    = (ushort*)p; p += (size_t)BS * NCH * LSEQ * 2;
    float*  partV = (float*)p;  p += (size_t)2 * BS * NCH * DIM * 4;   // 4 MB
    float*  w_v   = (float*)p;                                          // 33.5 MB

    float* out_vf = (float*)d_out;
    float* out_lg = out_vf + BS * NCH * DIM;

    k_prep<<<dim3(129), dim3(256), 0, stream>>>(Wv_w, BhiT, BloT, Wo_w, WohiT, WoloT,
                                                emb, embH, embL);
    k_gemm<<<dim3(516), dim3(256), 0, stream>>>(inp, BhiT, BloT, Wv_b, w_v,
                                                WohiT, WoloT, embH, embL, Wo_b, w_o);
    k_e<<<dim3(LSEQ / 16, BS, NCH / CHB), dim3(256), 0, stream>>>(w_v, w_o, We_w, ev);
    k_soft<<<dim3(256), dim3(256), 0, stream>>>(ev, aH, aL);
    k_vf<<<dim3(16, BS), dim3(256), 0, stream>>>(inp, aH, aL, partV);
    k_lg<<<dim3(256), dim3(256), 0, stream>>>(partV, Wc_w, Wc_b, out_vf, out_lg);
}